// Round 5
// baseline (122.963 us; speedup 1.0000x reference)
//
#include <hip/hip_runtime.h>
#include <math.h>

#define F 256
#define E 256
#define S 32
#define CH 4
#define LDK 40   // padded LDS k-stride (80 B rows: 16B-aligned, 2-way max bank alias)

typedef __attribute__((ext_vector_type(8))) short short8;
typedef __attribute__((ext_vector_type(4))) float f32x4;

__device__ __forceinline__ ushort f2bf(float x) {
    uint u = __float_as_uint(x);
    return (ushort)((u + 0x7fffu + ((u >> 16) & 1u)) >> 16);
}
__device__ __forceinline__ float bf2f(ushort h) {
    return __uint_as_float(((uint)h) << 16);
}
__device__ __forceinline__ void split4(const float* x, uint2& ph, uint2& pl) {
    ushort h[4], l[4];
#pragma unroll
    for (int i = 0; i < 4; ++i) { h[i] = f2bf(x[i]); l[i] = f2bf(x[i] - bf2f(h[i])); }
    ph.x = (uint)h[0] | ((uint)h[1] << 16); ph.y = (uint)h[2] | ((uint)h[3] << 16);
    pl.x = (uint)l[0] | ((uint)l[1] << 16); pl.y = (uint)l[2] | ((uint)l[3] << 16);
}
__device__ __forceinline__ uint4 pack8(const ushort* h) {
    uint4 r;
    r.x = (uint)h[0] | ((uint)h[1] << 16); r.y = (uint)h[2] | ((uint)h[3] << 16);
    r.z = (uint)h[4] | ((uint)h[5] << 16); r.w = (uint)h[6] | ((uint)h[7] << 16);
    return r;
}

// ---------------------------------------------------------------------------
// mfma_gemm (bf16x3 split): out[r][:] = X[idx?idx[r]:r][:] @ B + bias
// BM=64, BN=256 (full N), BK=32; 512 threads = 8 waves (2M x 4N), each wave
// 32x64 via 2x4 16x16x32 fragments.
// INSPLIT:  B given as f32 row-major BT_f32[col][k], split to hi/lo in-kernel.
//           else B given pre-split BTh/BTl (ushort bf16, [col][k]).
// OUTSPLIT: write hi/lo bf16 (for the MT prep); else f32 + bias.
// ---------------------------------------------------------------------------
template<bool INSPLIT, bool OUTSPLIT>
__global__ __launch_bounds__(512) void mfma_gemm(const float* __restrict__ X,
                                                 const int* __restrict__ idx,
                                                 const ushort* __restrict__ BTh,
                                                 const ushort* __restrict__ BTl,
                                                 const float* __restrict__ Bf,
                                                 const float* __restrict__ bias,
                                                 float* __restrict__ out,
                                                 ushort* __restrict__ outh,
                                                 ushort* __restrict__ outl,
                                                 int rows) {
    __shared__ ushort Ah[64][LDK], Al[64][LDK];
    __shared__ ushort Bh[256][LDK], Bl[256][LDK];

    const int tid = threadIdx.x;
    const int lane = tid & 63, wave = tid >> 6;
    const int wm = wave >> 2, wn = wave & 3;
    const int fr = lane & 15, fk = lane >> 4;
    const int row0 = blockIdx.x * 64;

    // A staging: thread -> row tid>>3, k-quad (tid&7)*4  (64 rows x 32 k f32)
    const int arL = tid >> 3;
    const int akL = (tid & 7) * 4;
    const int ar = row0 + arL;
    const int arc = ar < rows ? ar : rows - 1;
    const long arow = idx ? (long)idx[arc] : (long)arc;
    const float* aptr = X + arow * (long)F + akL;

    // B staging: thread -> col tid&255, k-half (tid>>8)*16
    const int bcol = tid & 255;
    const int bkh = (tid >> 8) * 16;

    f32x4 acc[2][4];
#pragma unroll
    for (int m = 0; m < 2; ++m)
#pragma unroll
        for (int n = 0; n < 4; ++n) acc[m][n] = (f32x4){0.f, 0.f, 0.f, 0.f};

    for (int k0 = 0; k0 < F; k0 += 32) {
        // global loads first (overlap with previous iteration's tail)
        const float4 av = *reinterpret_cast<const float4*>(&aptr[k0]);
        uint2 ah, al;
        split4(&av.x, ah, al);

        uint4 wh0, wh1, wl0, wl1;
        if constexpr (INSPLIT) {
            const float* bp = Bf + (size_t)bcol * F + k0 + bkh;
            float4 b0 = *reinterpret_cast<const float4*>(bp);
            float4 b1 = *reinterpret_cast<const float4*>(bp + 4);
            float4 b2 = *reinterpret_cast<const float4*>(bp + 8);
            float4 b3 = *reinterpret_cast<const float4*>(bp + 12);
            uint2 h0, l0, h1, l1, h2, l2, h3, l3;
            split4(&b0.x, h0, l0); split4(&b1.x, h1, l1);
            split4(&b2.x, h2, l2); split4(&b3.x, h3, l3);
            wh0 = make_uint4(h0.x, h0.y, h1.x, h1.y);
            wh1 = make_uint4(h2.x, h2.y, h3.x, h3.y);
            wl0 = make_uint4(l0.x, l0.y, l1.x, l1.y);
            wl1 = make_uint4(l2.x, l2.y, l3.x, l3.y);
        } else {
            const ushort* bph = BTh + (size_t)bcol * F + k0 + bkh;
            const ushort* bpl = BTl + (size_t)bcol * F + k0 + bkh;
            wh0 = *reinterpret_cast<const uint4*>(bph);
            wh1 = *reinterpret_cast<const uint4*>(bph + 8);
            wl0 = *reinterpret_cast<const uint4*>(bpl);
            wl1 = *reinterpret_cast<const uint4*>(bpl + 8);
        }

        __syncthreads();   // previous iteration's fragment reads complete
        *reinterpret_cast<uint2*>(&Ah[arL][akL]) = ah;
        *reinterpret_cast<uint2*>(&Al[arL][akL]) = al;
        *reinterpret_cast<uint4*>(&Bh[bcol][bkh]) = wh0;
        *reinterpret_cast<uint4*>(&Bh[bcol][bkh + 8]) = wh1;
        *reinterpret_cast<uint4*>(&Bl[bcol][bkh]) = wl0;
        *reinterpret_cast<uint4*>(&Bl[bcol][bkh + 8]) = wl1;
        __syncthreads();

        short8 a_h[2], a_l[2];
#pragma unroll
        for (int m = 0; m < 2; ++m) {
            a_h[m] = *reinterpret_cast<const short8*>(&Ah[wm * 32 + m * 16 + fr][fk * 8]);
            a_l[m] = *reinterpret_cast<const short8*>(&Al[wm * 32 + m * 16 + fr][fk * 8]);
        }
#pragma unroll
        for (int n = 0; n < 4; ++n) {
            const short8 b_h = *reinterpret_cast<const short8*>(&Bh[wn * 64 + n * 16 + fr][fk * 8]);
            const short8 b_l = *reinterpret_cast<const short8*>(&Bl[wn * 64 + n * 16 + fr][fk * 8]);
#pragma unroll
            for (int m = 0; m < 2; ++m) {
                acc[m][n] = __builtin_amdgcn_mfma_f32_16x16x32_bf16(a_h[m], b_h, acc[m][n], 0, 0, 0);
                acc[m][n] = __builtin_amdgcn_mfma_f32_16x16x32_bf16(a_h[m], b_l, acc[m][n], 0, 0, 0);
                acc[m][n] = __builtin_amdgcn_mfma_f32_16x16x32_bf16(a_l[m], b_h, acc[m][n], 0, 0, 0);
            }
        }
    }

    // epilogue: C/D map col = lane&15 (fr), row = fk*4 + reg  [m89-verified]
#pragma unroll
    for (int n = 0; n < 4; ++n) {
        const int col = wn * 64 + n * 16 + fr;
        float bb = 0.f;
        if constexpr (!OUTSPLIT) bb = bias[col];
#pragma unroll
        for (int m = 0; m < 2; ++m) {
#pragma unroll
            for (int r = 0; r < 4; ++r) {
                const int orow = row0 + wm * 32 + m * 16 + fk * 4 + r;
                if (orow < rows) {
                    if constexpr (OUTSPLIT) {
                        const float v = acc[m][n][r];
                        const ushort h = f2bf(v);
                        outh[(size_t)orow * F + col] = h;
                        outl[(size_t)orow * F + col] = f2bf(v - bf2f(h));
                    } else {
                        out[(size_t)orow * E + col] = acc[m][n][r] + bb;
                    }
                }
            }
        }
    }
}

// ---------------------------------------------------------------------------
// prep_misc: blocks 0..3   -> c[j] = Wk_j . bq   (coalesced row load + butterfly)
//            blocks 4..19  -> WvT[j][k] = Wv[k][j], split hi/lo (LDS transpose)
// ---------------------------------------------------------------------------
__global__ __launch_bounds__(256) void prep_misc(const float* __restrict__ Wk,
                                                 const float* __restrict__ bq,
                                                 const float* __restrict__ Wv,
                                                 float* __restrict__ c,
                                                 ushort* __restrict__ WvTh,
                                                 ushort* __restrict__ WvTl) {
    if (blockIdx.x < 4) {
        __shared__ float bqs[F];
        bqs[threadIdx.x] = bq[threadIdx.x];
        __syncthreads();
        const int lane = threadIdx.x & 63, w = threadIdx.x >> 6;
        const float4 b4 = *reinterpret_cast<const float4*>(&bqs[lane * 4]);
#pragma unroll
        for (int i = 0; i < 16; ++i) {
            const int j = blockIdx.x * 64 + w * 16 + i;
            const float4 k4 = *reinterpret_cast<const float4*>(&Wk[(size_t)j * F + lane * 4]);
            float p = k4.x * b4.x + k4.y * b4.y + k4.z * b4.z + k4.w * b4.w;
#pragma unroll
            for (int off = 32; off; off >>= 1) p += __shfl_xor(p, off);
            if (lane == 0) c[j] = p;
        }
    } else {
        __shared__ float t[64][65];
        const int tb = blockIdx.x - 4;
        const int jt = (tb & 3) * 64, kt = (tb >> 2) * 64;
        const int lk = threadIdx.x >> 2;
        const int lj = (threadIdx.x & 3) * 16;
#pragma unroll
        for (int u = 0; u < 16; u += 4) {
            const float4 v = *reinterpret_cast<const float4*>(&Wv[(size_t)(kt + lk) * E + jt + lj + u]);
            t[lk][lj + u] = v.x; t[lk][lj + u + 1] = v.y;
            t[lk][lj + u + 2] = v.z; t[lk][lj + u + 3] = v.w;
        }
        __syncthreads();
        const int oj = threadIdx.x >> 2;
        const int ok = (threadIdx.x & 3) * 16;
        ushort h[16], l[16];
#pragma unroll
        for (int u = 0; u < 16; ++u) {
            const float v = t[ok + u][oj];
            h[u] = f2bf(v); l[u] = f2bf(v - bf2f(h[u]));
        }
        ushort* ph = &WvTh[(size_t)(jt + oj) * F + kt + ok];
        ushort* pl = &WvTl[(size_t)(jt + oj) * F + kt + ok];
        *reinterpret_cast<uint4*>(ph) = pack8(h);
        *reinterpret_cast<uint4*>(ph + 8) = pack8(h + 8);
        *reinterpret_cast<uint4*>(pl) = pack8(l);
        *reinterpret_cast<uint4*>(pl + 8) = pack8(l + 8);
    }
}

// ---------------------------------------------------------------------------
// attn_gather (unchanged; at the random-gather memory wall ~60 us):
// one wave per node, single-pass online softmax, 4-row double-buffered chunks.
// ---------------------------------------------------------------------------
__device__ __forceinline__ void ld_chunk(float4* d, int idxv, int s0,
                                         const float* __restrict__ t, int lane) {
#pragma unroll
    for (int j = 0; j < CH; ++j) {
        const int nid = __builtin_amdgcn_readlane(idxv, s0 + j);
        d[j] = *reinterpret_cast<const float4*>(&t[(size_t)nid * F + lane * 4]);
    }
}

__device__ __forceinline__ void proc_chunk(const float4* v, const float4 qv,
                                           float& m, float& l, float4& acc) {
#pragma unroll
    for (int j = 0; j < CH; ++j) {
        float p = v[j].x * qv.x + v[j].y * qv.y + v[j].z * qv.z + v[j].w * qv.w;
#pragma unroll
        for (int off = 32; off; off >>= 1) p += __shfl_xor(p, off);
        if (p <= m) {
            const float w = __expf(p - m);
            l += w;
            acc.x += w * v[j].x; acc.y += w * v[j].y;
            acc.z += w * v[j].z; acc.w += w * v[j].w;
        } else {
            const float cc = __expf(m - p);
            l = l * cc + 1.f;
            acc.x = acc.x * cc + v[j].x; acc.y = acc.y * cc + v[j].y;
            acc.z = acc.z * cc + v[j].z; acc.w = acc.w * cc + v[j].w;
            m = p;
        }
    }
}

__global__ __launch_bounds__(256) void attn_gather(const int* __restrict__ neigh_idx,
                                                   const float* __restrict__ id2feat,
                                                   float* __restrict__ qtm,
                                                   int B) {
    const int node = blockIdx.x * 4 + (threadIdx.x >> 6);
    const int lane = threadIdx.x & 63;
    if (node >= B) return;

    const int idxv = neigh_idx[node * S + (lane & (S - 1))];
    const float4 qv = *reinterpret_cast<const float4*>(&qtm[(size_t)node * F + lane * 4]);

    float m = -INFINITY, l = 0.f;
    float4 acc = make_float4(0.f, 0.f, 0.f, 0.f);

    float4 va[CH], vb[CH];
    ld_chunk(va, idxv, 0, id2feat, lane);
    ld_chunk(vb, idxv, 4, id2feat, lane);
    proc_chunk(va, qv, m, l, acc);
    ld_chunk(va, idxv, 8, id2feat, lane);
    proc_chunk(vb, qv, m, l, acc);
    ld_chunk(vb, idxv, 12, id2feat, lane);
    proc_chunk(va, qv, m, l, acc);
    ld_chunk(va, idxv, 16, id2feat, lane);
    proc_chunk(vb, qv, m, l, acc);
    ld_chunk(vb, idxv, 20, id2feat, lane);
    proc_chunk(va, qv, m, l, acc);
    ld_chunk(va, idxv, 24, id2feat, lane);
    proc_chunk(vb, qv, m, l, acc);
    ld_chunk(vb, idxv, 28, id2feat, lane);
    proc_chunk(va, qv, m, l, acc);
    proc_chunk(vb, qv, m, l, acc);

    const float inv = 1.0f / l;
    float4 o;
    o.x = acc.x * inv; o.y = acc.y * inv; o.z = acc.z * inv; o.w = acc.w * inv;
    *reinterpret_cast<float4*>(&qtm[(size_t)node * F + lane * 4]) = o;
}

// ---------------------------------------------------------------------------
extern "C" void kernel_launch(void* const* d_in, const int* in_sizes, int n_in,
                              void* d_out, int out_size, void* d_ws, size_t ws_size,
                              hipStream_t stream) {
    const int*   nodes   = (const int*)d_in[0];
    const int*   neigh   = (const int*)d_in[1];
    const float* id2feat = (const float*)d_in[2];
    const float* Wq      = (const float*)d_in[3];
    const float* bq      = (const float*)d_in[4];
    const float* Wk      = (const float*)d_in[5];
    // d_in[6] = bk unused: softmax-invariant (self column masked).
    const float* Wv      = (const float*)d_in[7];
    const float* bv      = (const float*)d_in[8];
    float* out = (float*)d_out;
    const int B = in_sizes[0];

    ushort* MT_hi  = (ushort*)d_ws;          // 65536 each
    ushort* MT_lo  = MT_hi + 65536;
    ushort* WvT_hi = MT_lo + 65536;
    ushort* WvT_lo = WvT_hi + 65536;
    float*  cbuf   = (float*)(WvT_lo + 65536);
    float*  qtm    = cbuf + 256;             // [B][F]: q-tilde, then m (reused)

    // MT = Wk @ Wq^T (bf16x3 MFMA, B split from f32 in-kernel), output pre-split
    mfma_gemm<true, true><<<dim3(4), dim3(512), 0, stream>>>(
        Wk, nullptr, nullptr, nullptr, Wq, nullptr, nullptr, MT_hi, MT_lo, 256);
    // c = Wk @ bq; WvT = Wv^T split hi/lo
    prep_misc<<<dim3(20), dim3(256), 0, stream>>>(Wk, bq, Wv, cbuf, WvT_hi, WvT_lo);
    // q~ = gather(id2feat, nodes) @ M + c
    mfma_gemm<false, false><<<dim3((B + 63) / 64), dim3(512), 0, stream>>>(
        id2feat, nodes, MT_hi, MT_lo, nullptr, cbuf, qtm, nullptr, nullptr, B);
    // scores -> softmax -> m (in place over qtm)
    attn_gather<<<dim3((B + 3) / 4), dim3(256), 0, stream>>>(neigh, id2feat, qtm, B);
    // out = m @ Wv + bv
    mfma_gemm<false, false><<<dim3((B + 63) / 64), dim3(512), 0, stream>>>(
        qtm, nullptr, WvT_hi, WvT_lo, nullptr, bv, out, nullptr, nullptr, B);
}